// Round 15
// baseline (35.090 us; speedup 1.0000x reference)
//
#include <hip/hip_runtime.h>
#include <hip/hip_bf16.h>
#include <hip/hip_fp16.h>

// HeteroSoap via MFMA: c[s*4+n][ab] = sum_atoms f_sn * Y_ab = 16x16 GEMM, K=N.
// Round 15 = round-13 datapath VERBATIM (NB=512, packed-f16, best 17.69us),
// collapsed to ONE kernel: per-block result -> atomicAdd into c_ws (512
// adds/address, 8 cache lines), last-block ticket (pattern proven in
// soap_reduce_final r9-r14) runs the Yr/Yi/nnl finalize in-kernel.
// Deletes: 2nd launch, inter-kernel drain, 1 MB partials round-trip.
// hipMemsetAsync zeroes c_ws+counter per launch (replays don't re-poison).

typedef float f32x4 __attribute__((ext_vector_type(4)));
typedef unsigned int uint4v __attribute__((ext_vector_type(4)));
typedef _Float16 h2 __attribute__((ext_vector_type(2)));
typedef _Float16 half8 __attribute__((ext_vector_type(8)));

#define NB 512

__global__ void __launch_bounds__(256) soap_fused(
    const float* __restrict__ coo, const int* __restrict__ numbers,
    int N, float* __restrict__ c_ws, int* __restrict__ counter,
    float* __restrict__ out)
{
    __shared__ unsigned int lT[4][2][16][64];  // [wave][A|B][comp][pair] 32 KB
    __shared__ int lastflag;

    const int lane = threadIdx.x & 63;
    const int w = threadIdx.x >> 6;
    const int g = lane >> 4;            // k-group
    const int comp = lane & 15;         // fragment index dim (A row / B col)

    unsigned int* lA = &lT[w][0][0][0];
    unsigned int* lB = &lT[w][1][0][0];

    // Loop-invariant read offsets: MFMA m covers pairs 16m..16m+15; lane
    // (comp,g) reads 4 consecutive swizzled dwords = pairs 16m+4g..+3 =
    // atoms {16m+4g+j, 16m+4g+j+64}. Same map for A and B.
    const unsigned swz = (unsigned)((comp & 7) << 2);
    const unsigned rbase = (unsigned)(comp << 6);
    unsigned rd[4];
#pragma unroll
    for (int m = 0; m < 4; ++m)
        rd[m] = rbase + ((unsigned)(16 * m + 4 * g) ^ swz);

    f32x4 acc = {0.f, 0.f, 0.f, 0.f};

    const int stride = NB * 512;        // 4 waves x 128 atoms per block per iter
    for (int base = (blockIdx.x * 4 + w) * 128; base < N; base += stride) {
        int i0 = base + lane, i1 = base + 64 + lane;
        int ic0 = i0 < N ? i0 : N - 1, ic1 = i1 < N ? i1 : N - 1;
        float X0 = coo[3 * ic0], Y0_ = coo[3 * ic0 + 1], Z0 = coo[3 * ic0 + 2];
        float X1 = coo[3 * ic1], Y1_ = coo[3 * ic1 + 1], Z1 = coo[3 * ic1 + 2];
        int num0 = i0 < N ? numbers[ic0] : -1;
        int num1 = i1 < N ? numbers[ic1] : -1;

        // Radial in f32 per atom (exp-arg precision), store f16.
        float x0 = X0 * 0.5f, y0 = Y0_ * 0.5f, z0 = Z0 * 0.5f;
        float x1 = X1 * 0.5f, y1 = Y1_ * 0.5f, z1 = Z1 * 0.5f;
        float r20 = x0 * x0 + y0 * y0 + z0 * z0;
        float r21 = x1 * x1 + y1 * y1 + z1 * z1;
        float t0 = fmaxf(1.f - sqrtf(r20) * (1.f / 3.f), 0.f);
        float t1 = fmaxf(1.f - sqrtf(r21) * (1.f / 3.f), 0.f);
        float f00 = __expf(-0.5f * r20) * t0 * t0;
        float f01 = __expf(-0.5f * r21) * t1 * t1;

        h2 fpk[4];
        fpk[0] = (h2){(_Float16)f00, (_Float16)f01};
        fpk[1] = (h2){(_Float16)(f00 * r20), (_Float16)(f01 * r21)};
        fpk[2] = (h2){(_Float16)(f00 * r20 * r20), (_Float16)(f01 * r21 * r21)};
        fpk[3] = (h2){(_Float16)(f00 * r20 * r20 * r20), (_Float16)(f01 * r21 * r21 * r21)};

        // Species one-hot as f16 pair masks (invalid atom -> num=-1 -> 0).
        h2 msk[4];
#pragma unroll
        for (int s = 0; s < 4; ++s)
            msk[s] = (h2){(_Float16)(num0 == s ? 1.f : 0.f),
                          (_Float16)(num1 == s ? 1.f : 0.f)};

        // Packed f16 inputs for the harmonic chain (atom0 lo, atom1 hi).
        h2 xp = (h2){(_Float16)x0, (_Float16)x1};
        h2 yp = (h2){(_Float16)y0, (_Float16)y1};
        h2 zp = (h2){(_Float16)z0, (_Float16)z1};
        h2 rp = (h2){(_Float16)r20, (_Float16)r21};

        // Solid harmonics, packed pairs (v_pk_mul/fma_f16):
        h2 re11 = (_Float16)-0.34549414947133550f * xp;
        h2 im11 = (_Float16)-0.34549414947133550f * yp;
        h2 re10 = (_Float16) 0.48860251190291992f * zp;
        h2 re22 = (_Float16)-1.11803398874989490f * (xp * re11 - yp * im11);
        h2 im22 = (_Float16)-1.11803398874989490f * (xp * im11 + yp * re11);
        h2 re21 = (_Float16) 2.23606797749978970f * (zp * re11);
        h2 im21 = (_Float16) 2.23606797749978970f * (zp * im11);
        h2 re20 = (_Float16) 1.93649167310370850f * (zp * re10 - (_Float16)0.16286750396763996f * rp);
        h2 re33 = (_Float16)-1.08012344973464350f * (xp * re22 - yp * im22);
        h2 im33 = (_Float16)-1.08012344973464350f * (xp * im22 + yp * re22);
        h2 re32 = (_Float16) 2.64575131106459070f * (zp * re22);
        h2 im32 = (_Float16) 2.64575131106459070f * (zp * im22);
        h2 re31 = (_Float16) 2.09165006633518890f * (zp * re21 - (_Float16)0.44721359549995793f * (rp * re11));
        h2 im31 = (_Float16) 2.09165006633518890f * (zp * im21 - (_Float16)0.44721359549995793f * (rp * im11));
        h2 re30 = (_Float16) 1.97202659436653870f * (zp * re20 - (_Float16)0.51639777949432220f * (rp * re10));

        h2 ypk[16];
        ypk[0] = (h2){(_Float16)0.28209479177387814f, (_Float16)0.28209479177387814f};
        ypk[1] = im11; ypk[2]  = im22; ypk[3]  = im33;
        ypk[4] = re11; ypk[5]  = re10; ypk[6]  = im21; ypk[7]  = im32;
        ypk[8] = re22; ypk[9]  = re21; ypk[10] = re20; ypk[11] = im31;
        ypk[12] = re33; ypk[13] = re32; ypk[14] = re31; ypk[15] = re30;

        // Swizzled stores: lane owns pair-column `lane`; one b32 per tile/comp.
#pragma unroll
        for (int c = 0; c < 16; ++c) {
            h2 fs = fpk[c & 3] * msk[c >> 2];
            union { h2 h; unsigned u; } ua, ub;
            ua.h = fs; ub.h = ypk[c];
            unsigned idx = (unsigned)(c << 6) + ((unsigned)lane ^ ((unsigned)(c & 7) << 2));
            lA[idx] = ua.u;
            lB[idx] = ub.u;
        }

        // 4 MFMAs (32 atoms each); wave-private tile, in-order LDS per wave.
#pragma unroll
        for (int m = 0; m < 4; ++m) {
            union { uint4v q; half8 h; } A, B;
            A.q = *(const uint4v*)&lA[rd[m]];
            B.q = *(const uint4v*)&lB[rd[m]];
            acc = __builtin_amdgcn_mfma_f32_16x16x32_f16(A.h, B.h, acc, 0, 0, 0);
        }
    }

    // C/D layout (m89): lane, reg rr -> c[i=(lane>>4)*4+rr][j=lane&15].
    // Reuse this wave's (idle, wave-private) tile as the reduce buffer.
    float* credw = (float*)&lT[w][0][0][0];
#pragma unroll
    for (int rr = 0; rr < 4; ++rr)
        credw[((lane >> 4) * 4 + rr) * 16 + (lane & 15)] = acc[rr];
    __syncthreads();

    int tt = threadIdx.x;
    float v = ((float*)&lT[0][0][0][0])[tt] + ((float*)&lT[1][0][0][0])[tt] +
              ((float*)&lT[2][0][0][0])[tt] + ((float*)&lT[3][0][0][0])[tt];

    // Direct global accumulation: 512 adds/address over 8 cache lines.
    atomicAdd(&c_ws[tt], v);
    __syncthreads();                          // all 256 adds of this block issued
    if (tt == 0) {
        __threadfence();                      // release our adds
        lastflag = (atomicAdd(counter, 1) == NB - 1);
    }
    __syncthreads();
    if (!lastflag) return;

    // Last block: acquire everyone's adds, finalize, write out.
    __threadfence();
    __shared__ float cs[256];
    cs[tt] = __hip_atomic_load(&c_ws[tt], __ATOMIC_RELAXED,
                               __HIP_MEMORY_SCOPE_AGENT);  // L1-bypassing load
    __syncthreads();

    // p1[a,b,n,m,l] = sum_{j<=l} w_j c[b,m,l,j] c[a,n,l,j] (w=1 if j==l else 2)
    // p2[a,b,n,m,l] = sum_{i<l}  2  c[b,m,i,l] c[a,n,i,l]
    // out = (p1+p2) * nnl[n,m,l]
    const float fact[7] = {1.f, 1.f, 2.f, 6.f, 24.f, 120.f, 720.f};
#pragma unroll
    for (int k = 0; k < 4; ++k) {
        int o = k * 256 + tt;
        int l = o & 3, m = (o >> 2) & 3, n = (o >> 4) & 3,
            b = (o >> 6) & 3, a = (o >> 8) & 3;
        const float* cbm = &cs[(b * 4 + m) * 16];
        const float* can = &cs[(a * 4 + n) * 16];
        float vv = 0.f;
        for (int j = 0; j <= l; ++j) {
            float wgt = (j == l) ? 1.f : 2.f;
            vv += wgt * cbm[l * 4 + j] * can[l * 4 + j];
        }
        for (int i = 0; i < l; ++i)
            vv += 2.f * cbm[i * 4 + l] * can[i * 4 + l];
        float an = 1.0f / ((float)(2 * l + 1) * (float)(1 << (2 * n + l)) * fact[n] * fact[n + l]);
        float am = 1.0f / ((float)(2 * l + 1) * (float)(1 << (2 * m + l)) * fact[m] * fact[m + l]);
        out[o] = vv * sqrtf(an * am);
    }
}

extern "C" void kernel_launch(void* const* d_in, const int* in_sizes, int n_in,
                              void* d_out, int out_size, void* d_ws, size_t ws_size,
                              hipStream_t stream)
{
    const float* coo = (const float*)d_in[0];
    const int* numbers = (const int*)d_in[1];
    int N = in_sizes[1];                 // 1,000,000 atoms

    float* c_ws = (float*)d_ws;          // [256] accumulated c
    int* counter = (int*)((float*)d_ws + 256);  // ticket counter
    // ws requirement: 1028 bytes.

    hipMemsetAsync(d_ws, 0, 1028, stream);   // per-launch zero (capture-safe)
    hipLaunchKernelGGL(soap_fused, dim3(NB), dim3(256), 0, stream,
                       coo, numbers, N, c_ws, counter, (float*)d_out);
}

// Round 16
// 17.525 us; speedup vs baseline: 2.0023x; 2.0023x over previous
//
#include <hip/hip_runtime.h>
#include <hip/hip_bf16.h>
#include <hip/hip_fp16.h>

// HeteroSoap via MFMA: c[s*4+n][ab] = sum_atoms f_sn * Y_ab = 16x16 GEMM, K=N.
// Round 16 = round-13 (best, 17.69us) with ONE isolated change: each wave
// processes a FIXED 4 chunks and issues ALL 32 global loads up-front
// (independent batch) -> HBM latency paid once per wave, not once per chunk.
// Overflow chunks (base >= N) self-mask: num=-1 -> zero f-rows, clamped loads.
// Datapath (proven r13): packed-f16 harmonics (2 atoms/lane), radial in f32,
// staged dword = f16 pair, fragment = one ds_read_b128, zero unpack,
// v_mfma_f32_16x16x32_f16; same (pair,elem)->atom map for A and B so MFMA
// k-order cancels; XOR swizzle idx^((c&7)<<2) same on write and read;
// C/D layout per m89. Tail: partials + reduce/finalize ticket (r10 verbatim;
// r15 proved direct global atomics regress 2x - round-0 lesson).

typedef float f32x4 __attribute__((ext_vector_type(4)));
typedef unsigned int uint4v __attribute__((ext_vector_type(4)));
typedef _Float16 h2 __attribute__((ext_vector_type(2)));
typedef _Float16 half8 __attribute__((ext_vector_type(8)));

#define NB 512
#define NCH 4   // fixed chunks/wave: 2048 waves * 128 atoms * 4 = 1,048,576 >= N

__global__ void __launch_bounds__(256) soap_accum(
    const float* __restrict__ coo, const int* __restrict__ numbers,
    int N, float* __restrict__ partials, float* __restrict__ c_ws,
    int* __restrict__ counter)
{
    __shared__ unsigned int lT[4][2][16][64];  // [wave][A|B][comp][pair] 32 KB

    // Per-launch init of fused-tail state (accum ends before reduce starts).
    if (blockIdx.x == 0) {
        if (threadIdx.x < 256) c_ws[threadIdx.x] = 0.f;
        if (threadIdx.x == 0) *counter = 0;
    }

    const int lane = threadIdx.x & 63;
    const int w = threadIdx.x >> 6;
    const int g = lane >> 4;            // k-group
    const int comp = lane & 15;         // fragment index dim (A row / B col)

    unsigned int* lA = &lT[w][0][0][0];
    unsigned int* lB = &lT[w][1][0][0];

    const unsigned swz = (unsigned)((comp & 7) << 2);
    const unsigned rbase = (unsigned)(comp << 6);
    unsigned rd[4];
#pragma unroll
    for (int m = 0; m < 4; ++m)
        rd[m] = rbase + ((unsigned)(16 * m + 4 * g) ^ swz);

    f32x4 acc = {0.f, 0.f, 0.f, 0.f};

    // ---- ALL loads up-front: 4 chunks x (6 coo + 2 numbers), independent ----
    const int wid = blockIdx.x * 4 + w;
    float X0[NCH], Y0[NCH], Z0[NCH], X1[NCH], Y1[NCH], Z1[NCH];
    int n0[NCH], n1[NCH];
#pragma unroll
    for (int k = 0; k < NCH; ++k) {
        int base = (wid + k * 2048) * 128;
        int i0 = base + lane, i1 = base + 64 + lane;
        int ic0 = i0 < N ? i0 : N - 1, ic1 = i1 < N ? i1 : N - 1;
        X0[k] = coo[3 * ic0]; Y0[k] = coo[3 * ic0 + 1]; Z0[k] = coo[3 * ic0 + 2];
        X1[k] = coo[3 * ic1]; Y1[k] = coo[3 * ic1 + 1]; Z1[k] = coo[3 * ic1 + 2];
        n0[k] = i0 < N ? numbers[ic0] : -1;
        n1[k] = i1 < N ? numbers[ic1] : -1;
    }

#pragma unroll
    for (int k = 0; k < NCH; ++k) {
        int num0 = n0[k], num1 = n1[k];

        // Radial in f32 per atom (exp-arg precision), store f16.
        float x0 = X0[k] * 0.5f, y0 = Y0[k] * 0.5f, z0 = Z0[k] * 0.5f;
        float x1 = X1[k] * 0.5f, y1 = Y1[k] * 0.5f, z1 = Z1[k] * 0.5f;
        float r20 = x0 * x0 + y0 * y0 + z0 * z0;
        float r21 = x1 * x1 + y1 * y1 + z1 * z1;
        float t0 = fmaxf(1.f - sqrtf(r20) * (1.f / 3.f), 0.f);
        float t1 = fmaxf(1.f - sqrtf(r21) * (1.f / 3.f), 0.f);
        float f00 = __expf(-0.5f * r20) * t0 * t0;
        float f01 = __expf(-0.5f * r21) * t1 * t1;

        h2 fpk[4];
        fpk[0] = (h2){(_Float16)f00, (_Float16)f01};
        fpk[1] = (h2){(_Float16)(f00 * r20), (_Float16)(f01 * r21)};
        fpk[2] = (h2){(_Float16)(f00 * r20 * r20), (_Float16)(f01 * r21 * r21)};
        fpk[3] = (h2){(_Float16)(f00 * r20 * r20 * r20), (_Float16)(f01 * r21 * r21 * r21)};

        // Species one-hot as f16 pair masks (invalid atom -> num=-1 -> 0).
        h2 msk[4];
#pragma unroll
        for (int s = 0; s < 4; ++s)
            msk[s] = (h2){(_Float16)(num0 == s ? 1.f : 0.f),
                          (_Float16)(num1 == s ? 1.f : 0.f)};

        // Packed f16 inputs for the harmonic chain (atom0 lo, atom1 hi).
        h2 xp = (h2){(_Float16)x0, (_Float16)x1};
        h2 yp = (h2){(_Float16)y0, (_Float16)y1};
        h2 zp = (h2){(_Float16)z0, (_Float16)z1};
        h2 rp = (h2){(_Float16)r20, (_Float16)r21};

        // Solid harmonics, packed pairs (v_pk_mul/fma_f16):
        h2 re11 = (_Float16)-0.34549414947133550f * xp;
        h2 im11 = (_Float16)-0.34549414947133550f * yp;
        h2 re10 = (_Float16) 0.48860251190291992f * zp;
        h2 re22 = (_Float16)-1.11803398874989490f * (xp * re11 - yp * im11);
        h2 im22 = (_Float16)-1.11803398874989490f * (xp * im11 + yp * re11);
        h2 re21 = (_Float16) 2.23606797749978970f * (zp * re11);
        h2 im21 = (_Float16) 2.23606797749978970f * (zp * im11);
        h2 re20 = (_Float16) 1.93649167310370850f * (zp * re10 - (_Float16)0.16286750396763996f * rp);
        h2 re33 = (_Float16)-1.08012344973464350f * (xp * re22 - yp * im22);
        h2 im33 = (_Float16)-1.08012344973464350f * (xp * im22 + yp * re22);
        h2 re32 = (_Float16) 2.64575131106459070f * (zp * re22);
        h2 im32 = (_Float16) 2.64575131106459070f * (zp * im22);
        h2 re31 = (_Float16) 2.09165006633518890f * (zp * re21 - (_Float16)0.44721359549995793f * (rp * re11));
        h2 im31 = (_Float16) 2.09165006633518890f * (zp * im21 - (_Float16)0.44721359549995793f * (rp * im11));
        h2 re30 = (_Float16) 1.97202659436653870f * (zp * re20 - (_Float16)0.51639777949432220f * (rp * re10));

        h2 ypk[16];
        ypk[0] = (h2){(_Float16)0.28209479177387814f, (_Float16)0.28209479177387814f};
        ypk[1] = im11; ypk[2]  = im22; ypk[3]  = im33;
        ypk[4] = re11; ypk[5]  = re10; ypk[6]  = im21; ypk[7]  = im32;
        ypk[8] = re22; ypk[9]  = re21; ypk[10] = re20; ypk[11] = im31;
        ypk[12] = re33; ypk[13] = re32; ypk[14] = re31; ypk[15] = re30;

        // Swizzled stores: lane owns pair-column `lane`; one b32 per tile/comp.
#pragma unroll
        for (int c = 0; c < 16; ++c) {
            h2 fs = fpk[c & 3] * msk[c >> 2];
            union { h2 h; unsigned u; } ua, ub;
            ua.h = fs; ub.h = ypk[c];
            unsigned idx = (unsigned)(c << 6) + ((unsigned)lane ^ ((unsigned)(c & 7) << 2));
            lA[idx] = ua.u;
            lB[idx] = ub.u;
        }

        // 4 MFMAs (32 atoms each); wave-private tile, in-order LDS per wave.
#pragma unroll
        for (int m = 0; m < 4; ++m) {
            union { uint4v q; half8 h; } A, B;
            A.q = *(const uint4v*)&lA[rd[m]];
            B.q = *(const uint4v*)&lB[rd[m]];
            acc = __builtin_amdgcn_mfma_f32_16x16x32_f16(A.h, B.h, acc, 0, 0, 0);
        }
    }

    // C/D layout (m89): lane, reg rr -> c[i=(lane>>4)*4+rr][j=lane&15].
    // Reuse this wave's (idle, wave-private) tile as the reduce buffer.
    float* credw = (float*)&lT[w][0][0][0];
#pragma unroll
    for (int rr = 0; rr < 4; ++rr)
        credw[((lane >> 4) * 4 + rr) * 16 + (lane & 15)] = acc[rr];
    __syncthreads();

    int tt = threadIdx.x;
    partials[blockIdx.x * 256 + tt] =
        ((float*)&lT[0][0][0][0])[tt] + ((float*)&lT[1][0][0][0])[tt] +
        ((float*)&lT[2][0][0][0])[tt] + ((float*)&lT[3][0][0][0])[tt];
}

// Fused reduce + finalize, 32 blocks. Each block sums its slice of partials
// into c_ws atomically; last block to finish does the Yr/Yi/nnl contraction.
__global__ void __launch_bounds__(256) soap_reduce_final(
    const float* __restrict__ partials, float* __restrict__ c_ws,
    int* __restrict__ counter, float* __restrict__ out)
{
    __shared__ float cs[256];
    __shared__ int lastflag;
    int t = threadIdx.x;

    float v = 0.f;
    for (int r = blockIdx.x; r < NB; r += 32)
        v += partials[r * 256 + t];           // coalesced, 16 iters
    atomicAdd(&c_ws[t], v);                   // 32 adds/address, device scope
    __syncthreads();
    if (t == 0) {
        __threadfence();                      // release our adds
        lastflag = (atomicAdd(counter, 1) == 31);
    }
    __syncthreads();
    if (!lastflag) return;

    __threadfence();                          // acquire other blocks' adds
    cs[t] = __hip_atomic_load(&c_ws[t], __ATOMIC_RELAXED,
                              __HIP_MEMORY_SCOPE_AGENT);  // L1-bypassing load
    __syncthreads();

    // p1[a,b,n,m,l] = sum_{j<=l} w_j c[b,m,l,j] c[a,n,l,j] (w=1 if j==l else 2)
    // p2[a,b,n,m,l] = sum_{i<l}  2  c[b,m,i,l] c[a,n,i,l]
    // out = (p1+p2) * nnl[n,m,l]
    const float fact[7] = {1.f, 1.f, 2.f, 6.f, 24.f, 120.f, 720.f};
#pragma unroll
    for (int k = 0; k < 4; ++k) {
        int o = k * 256 + t;
        int l = o & 3, m = (o >> 2) & 3, n = (o >> 4) & 3,
            b = (o >> 6) & 3, a = (o >> 8) & 3;
        const float* cbm = &cs[(b * 4 + m) * 16];
        const float* can = &cs[(a * 4 + n) * 16];
        float vv = 0.f;
        for (int j = 0; j <= l; ++j) {
            float wgt = (j == l) ? 1.f : 2.f;
            vv += wgt * cbm[l * 4 + j] * can[l * 4 + j];
        }
        for (int i = 0; i < l; ++i)
            vv += 2.f * cbm[i * 4 + l] * can[i * 4 + l];
        float an = 1.0f / ((float)(2 * l + 1) * (float)(1 << (2 * n + l)) * fact[n] * fact[n + l]);
        float am = 1.0f / ((float)(2 * l + 1) * (float)(1 << (2 * m + l)) * fact[m] * fact[m + l]);
        out[o] = vv * sqrtf(an * am);
    }
}

extern "C" void kernel_launch(void* const* d_in, const int* in_sizes, int n_in,
                              void* d_out, int out_size, void* d_ws, size_t ws_size,
                              hipStream_t stream)
{
    const float* coo = (const float*)d_in[0];
    const int* numbers = (const int*)d_in[1];
    int N = in_sizes[1];                 // 1,000,000 atoms

    float* c_ws = (float*)d_ws;          // [256] accumulated c
    int* counter = (int*)((float*)d_ws + 256);  // ticket counter
    float* partials = (float*)d_ws + 512;       // [NB*256] stage-1 partials
    // ws requirement: (512 + 131072) * 4 B ~= 0.53 MB.

    hipLaunchKernelGGL(soap_accum, dim3(NB), dim3(256), 0, stream,
                       coo, numbers, N, partials, c_ws, counter);
    hipLaunchKernelGGL(soap_reduce_final, dim3(32), dim3(256), 0, stream,
                       partials, c_ws, counter, (float*)d_out);
}

// Round 17
// 17.223 us; speedup vs baseline: 2.0373x; 1.0175x over previous
//
#include <hip/hip_runtime.h>
#include <hip/hip_bf16.h>
#include <hip/hip_fp16.h>

// HeteroSoap via MFMA: c[s*4+n][ab] = sum_atoms f_sn * Y_ab = 16x16 GEMM, K=N.
// Round 17 = round-16 (best, 17.52us) with ONE isolated change: pair-dword
// now packs ADJACENT atoms (2p, 2p+1) instead of (p, p+64), so each lane's
// loads are 6 contiguous floats: 3x aligned float2 + 1x int2 = 16 contiguous
// VMEM insts/wave (was 32 stride-12 gathers touching each line 3x).
// Pair->k map changes identically for A and B (MFMA m still covers exactly
// atoms 32m..32m+31) -> k-order cancellation preserved (proven r5..r16).
// Datapath otherwise r16 verbatim: packed-f16 harmonics, radial f32, dword
// tile [comp][pair] XOR-swizzled idx^((c&7)<<2), one ds_read_b128/fragment,
// v_mfma_f32_16x16x32_f16, C/D per m89, loads hoisted (r16), NB=512,
// tail = partials + 32-block reduce/finalize ticket (r10).

typedef float f32x4 __attribute__((ext_vector_type(4)));
typedef unsigned int uint4v __attribute__((ext_vector_type(4)));
typedef _Float16 h2 __attribute__((ext_vector_type(2)));
typedef _Float16 half8 __attribute__((ext_vector_type(8)));

#define NB 512
#define NCH 4   // fixed chunks/wave: 2048 waves * 128 atoms * 4 = 1,048,576 >= N

__global__ void __launch_bounds__(256) soap_accum(
    const float* __restrict__ coo, const int* __restrict__ numbers,
    int N, float* __restrict__ partials, float* __restrict__ c_ws,
    int* __restrict__ counter)
{
    __shared__ unsigned int lT[4][2][16][64];  // [wave][A|B][comp][pair] 32 KB

    // Per-launch init of fused-tail state (accum ends before reduce starts).
    if (blockIdx.x == 0) {
        if (threadIdx.x < 256) c_ws[threadIdx.x] = 0.f;
        if (threadIdx.x == 0) *counter = 0;
    }

    const int lane = threadIdx.x & 63;
    const int w = threadIdx.x >> 6;
    const int g = lane >> 4;            // k-group
    const int comp = lane & 15;         // fragment index dim (A row / B col)

    unsigned int* lA = &lT[w][0][0][0];
    unsigned int* lB = &lT[w][1][0][0];

    // Read offsets: MFMA m reads 4 consecutive swizzled dwords = pairs
    // 16m+4g..+3 = atoms 32m+8g .. 32m+8g+7. Same map for A and B.
    const unsigned swz = (unsigned)((comp & 7) << 2);
    const unsigned rbase = (unsigned)(comp << 6);
    unsigned rd[4];
#pragma unroll
    for (int m = 0; m < 4; ++m)
        rd[m] = rbase + ((unsigned)(16 * m + 4 * g) ^ swz);

    f32x4 acc = {0.f, 0.f, 0.f, 0.f};

    // ---- ALL loads up-front, fully contiguous: lane owns atoms (2p, 2p+1) ---
    const int wid = blockIdx.x * 4 + w;
    float X0[NCH], Y0[NCH], Z0[NCH], X1[NCH], Y1[NCH], Z1[NCH];
    int n0[NCH], n1[NCH];
#pragma unroll
    for (int k = 0; k < NCH; ++k) {
        int base = (wid + k * 2048) * 128;
        int p = base + 2 * lane;            // first atom of this lane's pair
        int pc = p < N - 1 ? p : N - 2;     // clamp pair start (N even)
        const float* cb = coo + 3 * pc;     // 3*pc even -> 8B aligned
        float2 c0 = *(const float2*)(cb);
        float2 c1 = *(const float2*)(cb + 2);
        float2 c2 = *(const float2*)(cb + 4);
        X0[k] = c0.x; Y0[k] = c0.y; Z0[k] = c1.x;
        X1[k] = c1.y; Y1[k] = c2.x; Z1[k] = c2.y;
        int2 nm = *(const int2*)(numbers + pc);   // pc even -> 8B aligned
        n0[k] = p < N ? nm.x : -1;
        n1[k] = p + 1 < N ? nm.y : -1;
    }

#pragma unroll
    for (int k = 0; k < NCH; ++k) {
        int num0 = n0[k], num1 = n1[k];

        // Radial in f32 per atom (exp-arg precision), store f16.
        float x0 = X0[k] * 0.5f, y0 = Y0[k] * 0.5f, z0 = Z0[k] * 0.5f;
        float x1 = X1[k] * 0.5f, y1 = Y1[k] * 0.5f, z1 = Z1[k] * 0.5f;
        float r20 = x0 * x0 + y0 * y0 + z0 * z0;
        float r21 = x1 * x1 + y1 * y1 + z1 * z1;
        float t0 = fmaxf(1.f - sqrtf(r20) * (1.f / 3.f), 0.f);
        float t1 = fmaxf(1.f - sqrtf(r21) * (1.f / 3.f), 0.f);
        float f00 = __expf(-0.5f * r20) * t0 * t0;
        float f01 = __expf(-0.5f * r21) * t1 * t1;

        h2 fpk[4];
        fpk[0] = (h2){(_Float16)f00, (_Float16)f01};
        fpk[1] = (h2){(_Float16)(f00 * r20), (_Float16)(f01 * r21)};
        fpk[2] = (h2){(_Float16)(f00 * r20 * r20), (_Float16)(f01 * r21 * r21)};
        fpk[3] = (h2){(_Float16)(f00 * r20 * r20 * r20), (_Float16)(f01 * r21 * r21 * r21)};

        // Species one-hot as f16 pair masks (invalid atom -> num=-1 -> 0).
        h2 msk[4];
#pragma unroll
        for (int s = 0; s < 4; ++s)
            msk[s] = (h2){(_Float16)(num0 == s ? 1.f : 0.f),
                          (_Float16)(num1 == s ? 1.f : 0.f)};

        // Packed f16 inputs for the harmonic chain (atom 2p lo, atom 2p+1 hi).
        h2 xp = (h2){(_Float16)x0, (_Float16)x1};
        h2 yp = (h2){(_Float16)y0, (_Float16)y1};
        h2 zp = (h2){(_Float16)z0, (_Float16)z1};
        h2 rp = (h2){(_Float16)r20, (_Float16)r21};

        // Solid harmonics, packed pairs (v_pk_mul/fma_f16):
        h2 re11 = (_Float16)-0.34549414947133550f * xp;
        h2 im11 = (_Float16)-0.34549414947133550f * yp;
        h2 re10 = (_Float16) 0.48860251190291992f * zp;
        h2 re22 = (_Float16)-1.11803398874989490f * (xp * re11 - yp * im11);
        h2 im22 = (_Float16)-1.11803398874989490f * (xp * im11 + yp * re11);
        h2 re21 = (_Float16) 2.23606797749978970f * (zp * re11);
        h2 im21 = (_Float16) 2.23606797749978970f * (zp * im11);
        h2 re20 = (_Float16) 1.93649167310370850f * (zp * re10 - (_Float16)0.16286750396763996f * rp);
        h2 re33 = (_Float16)-1.08012344973464350f * (xp * re22 - yp * im22);
        h2 im33 = (_Float16)-1.08012344973464350f * (xp * im22 + yp * re22);
        h2 re32 = (_Float16) 2.64575131106459070f * (zp * re22);
        h2 im32 = (_Float16) 2.64575131106459070f * (zp * im22);
        h2 re31 = (_Float16) 2.09165006633518890f * (zp * re21 - (_Float16)0.44721359549995793f * (rp * re11));
        h2 im31 = (_Float16) 2.09165006633518890f * (zp * im21 - (_Float16)0.44721359549995793f * (rp * im11));
        h2 re30 = (_Float16) 1.97202659436653870f * (zp * re20 - (_Float16)0.51639777949432220f * (rp * re10));

        h2 ypk[16];
        ypk[0] = (h2){(_Float16)0.28209479177387814f, (_Float16)0.28209479177387814f};
        ypk[1] = im11; ypk[2]  = im22; ypk[3]  = im33;
        ypk[4] = re11; ypk[5]  = re10; ypk[6]  = im21; ypk[7]  = im32;
        ypk[8] = re22; ypk[9]  = re21; ypk[10] = re20; ypk[11] = im31;
        ypk[12] = re33; ypk[13] = re32; ypk[14] = re31; ypk[15] = re30;

        // Swizzled stores: lane owns pair-column `lane`; one b32 per tile/comp.
#pragma unroll
        for (int c = 0; c < 16; ++c) {
            h2 fs = fpk[c & 3] * msk[c >> 2];
            union { h2 h; unsigned u; } ua, ub;
            ua.h = fs; ub.h = ypk[c];
            unsigned idx = (unsigned)(c << 6) + ((unsigned)lane ^ ((unsigned)(c & 7) << 2));
            lA[idx] = ua.u;
            lB[idx] = ub.u;
        }

        // 4 MFMAs (32 atoms each); wave-private tile, in-order LDS per wave.
#pragma unroll
        for (int m = 0; m < 4; ++m) {
            union { uint4v q; half8 h; } A, B;
            A.q = *(const uint4v*)&lA[rd[m]];
            B.q = *(const uint4v*)&lB[rd[m]];
            acc = __builtin_amdgcn_mfma_f32_16x16x32_f16(A.h, B.h, acc, 0, 0, 0);
        }
    }

    // C/D layout (m89): lane, reg rr -> c[i=(lane>>4)*4+rr][j=lane&15].
    // Reuse this wave's (idle, wave-private) tile as the reduce buffer.
    float* credw = (float*)&lT[w][0][0][0];
#pragma unroll
    for (int rr = 0; rr < 4; ++rr)
        credw[((lane >> 4) * 4 + rr) * 16 + (lane & 15)] = acc[rr];
    __syncthreads();

    int tt = threadIdx.x;
    partials[blockIdx.x * 256 + tt] =
        ((float*)&lT[0][0][0][0])[tt] + ((float*)&lT[1][0][0][0])[tt] +
        ((float*)&lT[2][0][0][0])[tt] + ((float*)&lT[3][0][0][0])[tt];
}

// Fused reduce + finalize, 32 blocks. Each block sums its slice of partials
// into c_ws atomically; last block to finish does the Yr/Yi/nnl contraction.
__global__ void __launch_bounds__(256) soap_reduce_final(
    const float* __restrict__ partials, float* __restrict__ c_ws,
    int* __restrict__ counter, float* __restrict__ out)
{
    __shared__ float cs[256];
    __shared__ int lastflag;
    int t = threadIdx.x;

    float v = 0.f;
    for (int r = blockIdx.x; r < NB; r += 32)
        v += partials[r * 256 + t];           // coalesced, 16 iters
    atomicAdd(&c_ws[t], v);                   // 32 adds/address, device scope
    __syncthreads();
    if (t == 0) {
        __threadfence();                      // release our adds
        lastflag = (atomicAdd(counter, 1) == 31);
    }
    __syncthreads();
    if (!lastflag) return;

    __threadfence();                          // acquire other blocks' adds
    cs[t] = __hip_atomic_load(&c_ws[t], __ATOMIC_RELAXED,
                              __HIP_MEMORY_SCOPE_AGENT);  // L1-bypassing load
    __syncthreads();

    // p1[a,b,n,m,l] = sum_{j<=l} w_j c[b,m,l,j] c[a,n,l,j] (w=1 if j==l else 2)
    // p2[a,b,n,m,l] = sum_{i<l}  2  c[b,m,i,l] c[a,n,i,l]
    // out = (p1+p2) * nnl[n,m,l]
    const float fact[7] = {1.f, 1.f, 2.f, 6.f, 24.f, 120.f, 720.f};
#pragma unroll
    for (int k = 0; k < 4; ++k) {
        int o = k * 256 + t;
        int l = o & 3, m = (o >> 2) & 3, n = (o >> 4) & 3,
            b = (o >> 6) & 3, a = (o >> 8) & 3;
        const float* cbm = &cs[(b * 4 + m) * 16];
        const float* can = &cs[(a * 4 + n) * 16];
        float vv = 0.f;
        for (int j = 0; j <= l; ++j) {
            float wgt = (j == l) ? 1.f : 2.f;
            vv += wgt * cbm[l * 4 + j] * can[l * 4 + j];
        }
        for (int i = 0; i < l; ++i)
            vv += 2.f * cbm[i * 4 + l] * can[i * 4 + l];
        float an = 1.0f / ((float)(2 * l + 1) * (float)(1 << (2 * n + l)) * fact[n] * fact[n + l]);
        float am = 1.0f / ((float)(2 * l + 1) * (float)(1 << (2 * m + l)) * fact[m] * fact[m + l]);
        out[o] = vv * sqrtf(an * am);
    }
}

extern "C" void kernel_launch(void* const* d_in, const int* in_sizes, int n_in,
                              void* d_out, int out_size, void* d_ws, size_t ws_size,
                              hipStream_t stream)
{
    const float* coo = (const float*)d_in[0];
    const int* numbers = (const int*)d_in[1];
    int N = in_sizes[1];                 // 1,000,000 atoms

    float* c_ws = (float*)d_ws;          // [256] accumulated c
    int* counter = (int*)((float*)d_ws + 256);  // ticket counter
    float* partials = (float*)d_ws + 512;       // [NB*256] stage-1 partials
    // ws requirement: (512 + 131072) * 4 B ~= 0.53 MB.

    hipLaunchKernelGGL(soap_accum, dim3(NB), dim3(256), 0, stream,
                       coo, numbers, N, partials, c_ws, counter);
    hipLaunchKernelGGL(soap_reduce_final, dim3(32), dim3(256), 0, stream,
                       partials, c_ws, counter, (float*)d_out);
}